// Round 7
// baseline (340.057 us; speedup 1.0000x reference)
//
#include <hip/hip_runtime.h>
#include <hip/hip_cooperative_groups.h>

// ---------------------------------------------------------------------------
// cross_entropy_with_hnm_for_one_class_detection
//
// 3 scales: softmax-CE with hard-negative mining (k-th order statistic of
// neg_prob over N=B*H*W) + masked bbox MSE. Output: 3 floats.
//
// R6 bottleneck: structure. k_cand serialized on same-address reservation
// atomics (39us @ 0.4% VALU), 3-block kernels latency-bound, npv round-trip
// through HBM, 5 launches. R7: ONE cooperative kernel; np values live in
// registers across grid.sync(); redundant per-block bin-scan kills k_mid;
// block-aggregated candidate reservation (1 atomic/block).
// ---------------------------------------------------------------------------

namespace cg = cooperative_groups;

namespace {
constexpr int HW0 = 25600, HW1 = 6400, HW2 = 1600;
constexpr int N0 = 32 * HW0;  // 819200
constexpr int N1 = 32 * HW1;  // 204800
constexpr int N2 = 32 * HW2;  // 51200

constexpr int LBINS = 256;
constexpr int CAP = 8192;  // candidate capacity per scale

// 1024 elements per block (one float4-quad per thread)
constexpr int B0 = N0 / 1024, B1 = N1 / 1024, B2 = N2 / 1024;  // 800,200,50
constexpr int NBLK = B0 + B1 + B2;                             // 1050

struct P1 {
  double posce, diff2;
  unsigned int pcnt, ncnt;
  unsigned long long pad;
};  // 32 B
}  // namespace

__global__ __launch_bounds__(256, 5) void k_fused(
    const float* __restrict__ sc0, const float* __restrict__ bb0,
    const float* __restrict__ gl0, const float* __restrict__ sc1,
    const float* __restrict__ bb1, const float* __restrict__ gl1,
    const float* __restrict__ sc2, const float* __restrict__ bb2,
    const float* __restrict__ gl2, unsigned int* __restrict__ hist,
    float* __restrict__ histce, P1* __restrict__ part1,
    unsigned int* __restrict__ cand_cnt, unsigned int* __restrict__ cand,
    float* __restrict__ out) {
  cg::grid_group grid = cg::this_grid();
  const int tid = threadIdx.x;
  const int bid = blockIdx.x;

  int s, rel, HW, lo, hi;
  const float *sc, *bb, *gl;
  if (bid < B0) {
    s = 0; rel = bid; HW = HW0; lo = 0; hi = B0; sc = sc0; bb = bb0; gl = gl0;
  } else if (bid < B0 + B1) {
    s = 1; rel = bid - B0; HW = HW1; lo = B0; hi = B0 + B1;
    sc = sc1; bb = bb1; gl = gl1;
  } else {
    s = 2; rel = bid - B0 - B1; HW = HW2; lo = B0 + B1; hi = NBLK;
    sc = sc2; bb = bb2; gl = gl2;
  }

  // ---------------- phase 0: zero control region ----------------------------
  if (bid == 0) {
    for (int i = tid; i < 3 * LBINS; i += 256) {
      hist[i] = 0u;
      histce[i] = 0.0f;
    }
    if (tid < 3) cand_cnt[tid] = 0u;
  }
  grid.sync();

  // ---------------- phase A: softmax, counts, CE/bbox partials, hist --------
  __shared__ unsigned int lh[4][LBINS];
  __shared__ float lhe[4][LBINS];
  lh[0][tid] = 0u; lh[1][tid] = 0u; lh[2][tid] = 0u; lh[3][tid] = 0u;
  lhe[0][tid] = 0.0f; lhe[1][tid] = 0.0f; lhe[2][tid] = 0.0f; lhe[3][tid] = 0.0f;
  __syncthreads();

  const int wid = tid >> 6;
  double posce = 0.0, diff2 = 0.0;
  unsigned int pcnt = 0, ncnt = 0;
  float np[4];
  unsigned int bins[4];
  {
    const int q = (rel * 256 + tid) * 4;
    const int b = q / HW;
    const int hw = q - b * HW;
    const float* scp = sc + (size_t)b * 2 * HW + hw;
    const float4 s0v = *(const float4*)scp;
    const float4 s1v = *(const float4*)(scp + HW);
    const float* glp0 = gl + (size_t)b * 6 * HW + hw;
    const float4 l0v = *(const float4*)glp0;
    const float4 l1v = *(const float4*)(glp0 + HW);
    const float s0a[4] = {s0v.x, s0v.y, s0v.z, s0v.w};
    const float s1a[4] = {s1v.x, s1v.y, s1v.z, s1v.w};
    const float l0a[4] = {l0v.x, l0v.y, l0v.z, l0v.w};
    const float l1a[4] = {l1v.x, l1v.y, l1v.z, l1v.w};
#pragma unroll
    for (int j = 0; j < 4; ++j) {
      const float d = s1a[j] - s0a[j];
      const float t = expf(-fabsf(d));
      const float l1p = log1pf(t);  // lse after max-sub
      const bool pos = l0a[j] > 0.5f;
      const bool neg = l1a[j] > 0.5f;
      const float sm1 = ((d >= 0.0f) ? 1.0f : t) / (1.0f + t);
      const float v = neg ? sm1 : 0.0f;
      np[j] = v;
      unsigned int bin = (unsigned int)(v * 256.0f);
      bin = bin > 255u ? 255u : bin;
      bins[j] = bin;
      atomicAdd(&lh[wid][bin], 1u);
      if (neg) {
        ncnt++;
        const float ce = l1p - ((d >= 0.0f) ? 0.0f : d);  // -log_softmax[1]
        atomicAdd(&lhe[wid][bin], ce);
      }
      if (pos) {
        pcnt++;
        const float ls0 = ((d > 0.0f) ? -d : 0.0f) - l1p;
        posce += (double)(-l0a[j] * ls0);
        const float* glp = glp0 + j;
        const float* bbp = bb + (size_t)b * 4 * HW + hw + j;
        float acc = 0.0f;
#pragma unroll
        for (int c = 0; c < 4; ++c) {
          const float dd = glp[(2 + c) * HW] - bbp[c * HW];
          acc += dd * dd;
        }
        diff2 += (double)acc;
      }
    }
  }
  __syncthreads();
  {  // flush wave-private hists: one global atomic per thread per array
    const unsigned int c = lh[0][tid] + lh[1][tid] + lh[2][tid] + lh[3][tid];
    if (c) atomicAdd(&hist[s * LBINS + tid], c);
    const float e = lhe[0][tid] + lhe[1][tid] + lhe[2][tid] + lhe[3][tid];
    if (e != 0.0f) atomicAdd(&histce[s * LBINS + tid], e);
  }

  // block-reduce partials -> part1[bid]
  __shared__ double sda[256], sdb[256];
  __shared__ unsigned int sua[256], sub[256];
  sda[tid] = posce;
  sdb[tid] = diff2;
  sua[tid] = pcnt;
  sub[tid] = ncnt;
  __syncthreads();
  for (int o = 128; o > 0; o >>= 1) {
    if (tid < o) {
      sda[tid] += sda[tid + o];
      sdb[tid] += sdb[tid + o];
      sua[tid] += sua[tid + o];
      sub[tid] += sub[tid + o];
    }
    __syncthreads();
  }
  if (tid == 0) {
    part1[bid].posce = sda[0];
    part1[bid].diff2 = sdb[0];
    part1[bid].pcnt = sua[0];
    part1[bid].ncnt = sub[0];
  }
  grid.sync();

  // ---------------- phase B (redundant per block): totals + bin scan --------
  __shared__ double sh_posce, sh_diff2, sh_ce_below;
  __shared__ unsigned int sh_pcnt, sh_k, sh_selb, sh_selr;
  {
    double a = 0.0, b2 = 0.0;
    unsigned int c = 0, d = 0;
    for (int i = lo + tid; i < hi; i += 256) {
      const P1 p = part1[i];
      a += p.posce;
      b2 += p.diff2;
      c += p.pcnt;
      d += p.ncnt;
    }
    sda[tid] = a; sdb[tid] = b2; sua[tid] = c; sub[tid] = d;
  }
  __syncthreads();
  for (int o = 128; o > 0; o >>= 1) {
    if (tid < o) {
      sda[tid] += sda[tid + o];
      sdb[tid] += sdb[tid + o];
      sua[tid] += sua[tid + o];
      sub[tid] += sub[tid + o];
    }
    __syncthreads();
  }
  if (tid == 0) {
    sh_posce = sda[0];
    sh_diff2 = sdb[0];
    sh_pcnt = sua[0];
    const unsigned long long k10 = 10ull * (unsigned long long)sua[0];
    sh_k = (k10 < (unsigned long long)sub[0]) ? (unsigned int)k10 : sub[0];
  }
  __syncthreads();

  // dual inclusive scan over 256 bins (one bin per thread)
  __shared__ unsigned int partC[256];
  __shared__ double partE[256];
  const unsigned int ownC = hist[s * LBINS + tid];
  const double ownE = (double)histce[s * LBINS + tid];
  partC[tid] = ownC;
  partE[tid] = ownE;
  __syncthreads();
  for (int o = 1; o < 256; o <<= 1) {
    const unsigned int aC = (tid >= o) ? partC[tid - o] : 0u;
    const double aE = (tid >= o) ? partE[tid - o] : 0.0;
    __syncthreads();
    partC[tid] += aC;
    partE[tid] += aE;
    __syncthreads();
  }
  {
    const unsigned int k = sh_k;
    const unsigned int inclC = partC[tid];
    const unsigned int exclC = inclC - ownC;
    if (ownC && k >= exclC && k < inclC) {  // unique winner thread
      sh_selb = (unsigned int)tid;
      sh_selr = k - exclC;
      sh_ce_below = partE[tid] - ownE;  // exclusive CE prefix
    }
  }
  __syncthreads();

  // ---------------- phase C: gather candidates from registers ---------------
  __shared__ unsigned int cbuf[1024];
  __shared__ unsigned int ccnt, cbase;
  if (tid == 0) ccnt = 0u;
  __syncthreads();
  {
    const unsigned int bsel = sh_selb;
#pragma unroll
    for (int j = 0; j < 4; ++j) {
      if (bins[j] == bsel) {
        const unsigned int sl = atomicAdd(&ccnt, 1u);
        cbuf[sl] = __float_as_uint(np[j]);
      }
    }
  }
  __syncthreads();
  if (tid == 0 && ccnt) cbase = atomicAdd(&cand_cnt[s], ccnt);
  __syncthreads();
  for (unsigned int i = tid; i < ccnt; i += 256) {
    const unsigned int idx = cbase + i;
    if (idx < CAP) cand[s * CAP + idx] = cbuf[i];
  }
  grid.sync();

  // ---------------- phase D: 3 blocks radix-select + finalize ---------------
  if (rel != 0) return;
  const unsigned int n = min(cand_cnt[s], (unsigned int)CAP);
  const unsigned int* lst = cand + s * CAP;
  __shared__ unsigned int dh[256];
  __shared__ unsigned int shp, shr;
  if (tid == 0) {
    shp = 0u;
    shr = sh_selr;
  }
  __syncthreads();
#pragma unroll
  for (int round = 0; round < 4; ++round) {
    const int shift = 24 - 8 * round;
    dh[tid] = 0u;
    __syncthreads();
    const unsigned int pref = shp;
    for (unsigned int i = tid; i < n; i += 256) {
      const unsigned int v = lst[i];
      const bool match =
          (round == 0) || ((v >> (shift + 8)) == (pref >> (shift + 8)));
      if (match) atomicAdd(&dh[(v >> shift) & 255u], 1u);
    }
    __syncthreads();
    if (tid == 0) {
      unsigned int k = shr, run = 0, sel = 255;
      for (int bkt = 0; bkt < 256; ++bkt) {
        const unsigned int c = dh[bkt];
        if (run + c > k) { sel = (unsigned int)bkt; break; }
        run += c;
      }
      shp = pref | (sel << shift);
      shr = k - run;
    }
    __syncthreads();
  }
  const float thr = __uint_as_float(shp);

  // in-bin CE: candidates with 0 < v <= thr (v==0 -> non-neg -> ce 0)
  double acc = 0.0;
  for (unsigned int i = tid; i < n; i += 256) {
    const float v = __uint_as_float(lst[i]);
    if (v > 0.0f && v <= thr) acc += (double)(-logf(v));
  }
  sda[tid] = acc;
  __syncthreads();
  for (int o = 128; o > 0; o >>= 1) {
    if (tid < o) sda[tid] += sda[tid + o];
    __syncthreads();
  }
  if (tid == 0) {
    const double Ns = (s == 0) ? (double)N0 : (s == 1) ? (double)N1 : (double)N2;
    const double W = (s == 0) ? 160.0 : (s == 1) ? 80.0 : 40.0;
    const double ls = (sh_posce + sh_ce_below + sda[0]) / (2.0 * Ns);
    const double lb = (sh_diff2 / W) / (4.0 * (double)sh_pcnt);
    out[s] = (float)(ls + lb);
  }
}

extern "C" void kernel_launch(void* const* d_in, const int* in_sizes, int n_in,
                              void* d_out, int out_size, void* d_ws,
                              size_t ws_size, hipStream_t stream) {
  const float* sc0 = (const float*)d_in[0];
  const float* bb0 = (const float*)d_in[1];
  const float* gl0 = (const float*)d_in[3];
  const float* sc1 = (const float*)d_in[4];
  const float* bb1 = (const float*)d_in[5];
  const float* gl1 = (const float*)d_in[7];
  const float* sc2 = (const float*)d_in[8];
  const float* bb2 = (const float*)d_in[9];
  const float* gl2 = (const float*)d_in[11];

  char* ws = (char*)d_ws;
  unsigned int* hist = (unsigned int*)ws;               // 3*256 u32
  float* histce = (float*)(hist + 3 * LBINS);           // 3*256 f32
  unsigned int* cand_cnt = (unsigned int*)(histce + 3 * LBINS);  // 3 u32
  size_t off = (size_t)3 * LBINS * 4 * 2 + 64;
  off = (off + 255) & ~(size_t)255;
  P1* part1 = (P1*)(ws + off);                          // NBLK * 32 B
  off += (size_t)NBLK * sizeof(P1);
  off = (off + 255) & ~(size_t)255;
  unsigned int* cand = (unsigned int*)(ws + off);       // 3*CAP u32
  float* out = (float*)d_out;

  void* args[] = {&sc0, &bb0, &gl0, &sc1, &bb1, &gl1, &sc2, &bb2, &gl2,
                  &hist, &histce, &part1, &cand_cnt, &cand, &out};
  hipLaunchCooperativeKernel((void*)k_fused, dim3(NBLK), dim3(256), args, 0,
                             stream);
}

// Round 8
// 91.566 us; speedup vs baseline: 3.7138x; 3.7138x over previous
//
#include <hip/hip_runtime.h>

// ---------------------------------------------------------------------------
// cross_entropy_with_hnm_for_one_class_detection
//
// 3 scales: softmax-CE with hard-negative mining (k-th order statistic of
// neg_prob over N=B*H*W) + masked bbox MSE. Output: 3 floats.
//
// R7 lesson: cooperative grid.sync() ~100us each on MI355X (8-XCD system-
// scope spin) -- 3 syncs = 300us of idle. R8: same phases as stream-ordered
// kernels (launch overhead ~2us each beats grid.sync by 50x):
//   k_zero -> k_pass1 (fused softmax/CE/bbox/hist, slim LDS, shuffle
//   reductions) -> k_cand (redundant bin-scan + block-aggregated candidate
//   reservation) -> k_select (exact radix select + finalize).
// ---------------------------------------------------------------------------

namespace {
constexpr int HW0 = 25600, HW1 = 6400, HW2 = 1600;
constexpr int N0 = 32 * HW0;  // 819200
constexpr int N1 = 32 * HW1;  // 204800
constexpr int N2 = 32 * HW2;  // 51200

constexpr int LBINS = 256;
constexpr int CAP = 8192;  // candidate capacity per scale

// 1024 elements per block (one float4-quad per thread)
constexpr int B0 = N0 / 1024, B1 = N1 / 1024, B2 = N2 / 1024;  // 800,200,50
constexpr int NBLK = B0 + B1 + B2;                             // 1050

struct ScaleScal {
  unsigned int pos_cnt, sel_rank, pad0, pad1;
  double sum_pos_ce, sum_diff2, ce_below;
};  // 40 B

struct P1 {
  double posce, diff2;
  unsigned int pcnt, ncnt;
  unsigned long long pad;
};  // 32 B

__device__ inline void scale_of(int bid, int& s, int& rel, int& lo, int& hi) {
  if (bid < B0) {
    s = 0; rel = bid; lo = 0; hi = B0;
  } else if (bid < B0 + B1) {
    s = 1; rel = bid - B0; lo = B0; hi = B0 + B1;
  } else {
    s = 2; rel = bid - B0 - B1; lo = B0 + B1; hi = NBLK;
  }
}
}  // namespace

// ---------------- pass 0: zero control region (6.4 KB) ----------------------
__global__ __launch_bounds__(256) void k_zero(uint4* __restrict__ p, int n4) {
  for (int i = threadIdx.x; i < n4; i += 256) p[i] = make_uint4(0u, 0u, 0u, 0u);
}

// ---------------- pass 1: softmax, counts, pos-CE, bbox, hist + CE hist -----
template <int HW>
__device__ void pass1_body(int rel, const float* __restrict__ sc,
                           const float* __restrict__ bb,
                           const float* __restrict__ gl,
                           unsigned int* __restrict__ hist,
                           float* __restrict__ histce,
                           float* __restrict__ npv, P1* __restrict__ p1) {
  __shared__ unsigned int lh[4][LBINS];  // 4 KiB, wave-private
  __shared__ float lhe[4][LBINS];        // 4 KiB
  const int tid = threadIdx.x;
  const int wid = tid >> 6;
#pragma unroll
  for (int w = 0; w < 4; ++w) {
    lh[w][tid] = 0u;
    lhe[w][tid] = 0.0f;
  }
  __syncthreads();

  double posce = 0.0, diff2 = 0.0;
  unsigned int pcnt = 0, ncnt = 0;
  {
    const int q = (rel * 256 + tid) * 4;
    const int b = q / HW;
    const int hw = q - b * HW;
    const float* scp = sc + (size_t)b * 2 * HW + hw;
    const float4 s0v = *(const float4*)scp;
    const float4 s1v = *(const float4*)(scp + HW);
    const float* glp0 = gl + (size_t)b * 6 * HW + hw;
    const float4 l0v = *(const float4*)glp0;
    const float4 l1v = *(const float4*)(glp0 + HW);
    const float s0a[4] = {s0v.x, s0v.y, s0v.z, s0v.w};
    const float s1a[4] = {s1v.x, s1v.y, s1v.z, s1v.w};
    const float l0a[4] = {l0v.x, l0v.y, l0v.z, l0v.w};
    const float l1a[4] = {l1v.x, l1v.y, l1v.z, l1v.w};
    float np[4];
#pragma unroll
    for (int j = 0; j < 4; ++j) {
      const float d = s1a[j] - s0a[j];
      const float t = expf(-fabsf(d));
      const float l1p = log1pf(t);  // lse after max-sub
      const bool pos = l0a[j] > 0.5f;
      const bool neg = l1a[j] > 0.5f;
      const float sm1 = ((d >= 0.0f) ? 1.0f : t) / (1.0f + t);
      const float v = neg ? sm1 : 0.0f;
      np[j] = v;
      unsigned int bin = (unsigned int)(v * 256.0f);
      bin = bin > 255u ? 255u : bin;
      atomicAdd(&lh[wid][bin], 1u);
      if (neg) {
        ncnt++;
        const float ce = l1p - ((d >= 0.0f) ? 0.0f : d);  // -log_softmax[1]
        atomicAdd(&lhe[wid][bin], ce);
      }
      if (pos) {
        pcnt++;
        const float ls0 = ((d > 0.0f) ? -d : 0.0f) - l1p;
        posce += (double)(-l0a[j] * ls0);
        const float* glp = glp0 + j;
        const float* bbp = bb + (size_t)b * 4 * HW + hw + j;
        float acc = 0.0f;
#pragma unroll
        for (int c = 0; c < 4; ++c) {
          const float dd = glp[(2 + c) * HW] - bbp[c * HW];
          acc += dd * dd;
        }
        diff2 += (double)acc;
      }
    }
    *(float4*)(npv + q) = make_float4(np[0], np[1], np[2], np[3]);
  }
  __syncthreads();
  {  // flush: one bin per thread per array
    const unsigned int c = lh[0][tid] + lh[1][tid] + lh[2][tid] + lh[3][tid];
    if (c) atomicAdd(&hist[tid], c);  // u32 HW atomic
    const float e = lhe[0][tid] + lhe[1][tid] + lhe[2][tid] + lhe[3][tid];
    if (e != 0.0f) atomicAdd(&histce[tid], e);  // f32 HW atomic
  }

  // wave shuffle-reduce, then 4 partials -> thread 0
  for (int o = 32; o > 0; o >>= 1) {
    posce += __shfl_down(posce, o, 64);
    diff2 += __shfl_down(diff2, o, 64);
    pcnt += __shfl_down(pcnt, o, 64);
    ncnt += __shfl_down(ncnt, o, 64);
  }
  __shared__ double wa[4], wb[4];
  __shared__ unsigned int wc[4], wd[4];
  if ((tid & 63) == 0) {
    wa[wid] = posce; wb[wid] = diff2; wc[wid] = pcnt; wd[wid] = ncnt;
  }
  __syncthreads();
  if (tid == 0) {
    p1->posce = wa[0] + wa[1] + wa[2] + wa[3];
    p1->diff2 = wb[0] + wb[1] + wb[2] + wb[3];
    p1->pcnt = wc[0] + wc[1] + wc[2] + wc[3];
    p1->ncnt = wd[0] + wd[1] + wd[2] + wd[3];
  }
}

__global__ __launch_bounds__(256, 4) void k_pass1(
    const float* sc0, const float* bb0, const float* gl0,
    const float* sc1, const float* bb1, const float* gl1,
    const float* sc2, const float* bb2, const float* gl2,
    unsigned int* hist, float* histce, float* npv, P1* part1) {
  int s, rel, lo, hi;
  scale_of(blockIdx.x, s, rel, lo, hi);
  P1* p1 = part1 + blockIdx.x;
  if (s == 0)
    pass1_body<HW0>(rel, sc0, bb0, gl0, hist, histce, npv, p1);
  else if (s == 1)
    pass1_body<HW1>(rel, sc1, bb1, gl1, hist + LBINS, histce + LBINS, npv + N0,
                    p1);
  else
    pass1_body<HW2>(rel, sc2, bb2, gl2, hist + 2 * LBINS, histce + 2 * LBINS,
                    npv + N0 + N1, p1);
}

// ------ pass 2: redundant mid (reduce partials + bin scan) + gather ---------
__global__ __launch_bounds__(256) void k_cand(
    const P1* __restrict__ part1, const unsigned int* __restrict__ hist,
    const float* __restrict__ histce, const float* __restrict__ npv,
    ScaleScal* __restrict__ scal, unsigned int* __restrict__ cand_cnt,
    unsigned int* __restrict__ cand) {
  const int tid = threadIdx.x;
  int s, rel, lo, hi;
  scale_of(blockIdx.x, s, rel, lo, hi);
  const int base = (s == 0) ? 0 : (s == 1) ? N0 : N0 + N1;

  // ---- redundant per-block: reduce per-block partials of this scale
  __shared__ double sda[256], sdb[256];
  __shared__ unsigned int sua[256], sub[256];
  {
    double a = 0.0, b2 = 0.0;
    unsigned int c = 0, d = 0;
    for (int i = lo + tid; i < hi; i += 256) {
      const P1 p = part1[i];
      a += p.posce; b2 += p.diff2; c += p.pcnt; d += p.ncnt;
    }
    sda[tid] = a; sdb[tid] = b2; sua[tid] = c; sub[tid] = d;
  }
  __syncthreads();
  for (int o = 128; o > 0; o >>= 1) {
    if (tid < o) {
      sda[tid] += sda[tid + o]; sdb[tid] += sdb[tid + o];
      sua[tid] += sua[tid + o]; sub[tid] += sub[tid + o];
    }
    __syncthreads();
  }
  __shared__ unsigned int sh_k;
  if (tid == 0) {
    const unsigned long long k10 = 10ull * (unsigned long long)sua[0];
    sh_k = (k10 < (unsigned long long)sub[0]) ? (unsigned int)k10 : sub[0];
  }
  __syncthreads();

  // ---- redundant per-block: dual inclusive scan over 256 bins
  __shared__ unsigned int partC[256];
  __shared__ double partE[256];
  __shared__ unsigned int sh_selb, sh_selr;
  __shared__ double sh_ceb;
  const unsigned int ownC = hist[s * LBINS + tid];
  const double ownE = (double)histce[s * LBINS + tid];
  partC[tid] = ownC;
  partE[tid] = ownE;
  __syncthreads();
  for (int o = 1; o < 256; o <<= 1) {
    const unsigned int aC = (tid >= o) ? partC[tid - o] : 0u;
    const double aE = (tid >= o) ? partE[tid - o] : 0.0;
    __syncthreads();
    partC[tid] += aC;
    partE[tid] += aE;
    __syncthreads();
  }
  {
    const unsigned int k = sh_k;
    const unsigned int inclC = partC[tid];
    const unsigned int exclC = inclC - ownC;
    if (ownC && k >= exclC && k < inclC) {  // unique winner thread
      sh_selb = (unsigned int)tid;
      sh_selr = k - exclC;
      sh_ceb = partE[tid] - ownE;  // exclusive CE prefix
    }
  }
  __syncthreads();

  if (rel == 0 && tid == 0) {  // one block per scale publishes scalars
    scal[s].pos_cnt = sua[0];
    scal[s].sel_rank = sh_selr;
    scal[s].sum_pos_ce = sda[0];
    scal[s].sum_diff2 = sdb[0];
    scal[s].ce_below = sh_ceb;
  }

  // ---- gather candidates: block-aggregated reservation (1 atomic/block)
  __shared__ unsigned int cbuf[1024];
  __shared__ unsigned int ccnt, cbase;
  if (tid == 0) ccnt = 0u;
  __syncthreads();
  {
    const unsigned int bsel = sh_selb;
    const int q = (rel * 256 + tid) * 4;
    const float4 v4 = *(const float4*)(npv + base + q);
    const float va[4] = {v4.x, v4.y, v4.z, v4.w};
#pragma unroll
    for (int j = 0; j < 4; ++j) {
      unsigned int bin = (unsigned int)(va[j] * 256.0f);
      bin = bin > 255u ? 255u : bin;
      if (bin == bsel) {
        const unsigned int sl = atomicAdd(&ccnt, 1u);
        cbuf[sl] = __float_as_uint(va[j]);
      }
    }
  }
  __syncthreads();
  if (tid == 0 && ccnt) cbase = atomicAdd(&cand_cnt[s], ccnt);
  __syncthreads();
  const unsigned int cn = ccnt;
  for (unsigned int i = tid; i < cn; i += 256) {
    const unsigned int idx = cbase + i;
    if (idx < CAP) cand[s * CAP + idx] = cbuf[i];
  }
}

// ------- pass 3: radix select over candidates; in-bin CE; final outputs -----
__global__ __launch_bounds__(256) void k_select(
    const ScaleScal* __restrict__ scal, const unsigned int* __restrict__ cand_cnt,
    const unsigned int* __restrict__ cand, float* __restrict__ out) {
  const int s = blockIdx.x;
  const int tid = threadIdx.x;
  const unsigned int n = min(cand_cnt[s], (unsigned int)CAP);
  const unsigned int* lst = cand + s * CAP;
  __shared__ unsigned int dh[256];
  __shared__ unsigned int shp, shr;
  if (tid == 0) {
    shp = 0u;
    shr = scal[s].sel_rank;
  }
  __syncthreads();
#pragma unroll
  for (int round = 0; round < 4; ++round) {
    const int shift = 24 - 8 * round;
    dh[tid] = 0u;
    __syncthreads();
    const unsigned int pref = shp;
    for (unsigned int i = tid; i < n; i += 256) {
      const unsigned int v = lst[i];
      const bool match =
          (round == 0) || ((v >> (shift + 8)) == (pref >> (shift + 8)));
      if (match) atomicAdd(&dh[(v >> shift) & 255u], 1u);
    }
    __syncthreads();
    if (tid == 0) {
      unsigned int k = shr, run = 0, sel = 255;
      for (int bkt = 0; bkt < 256; ++bkt) {
        const unsigned int c = dh[bkt];
        if (run + c > k) { sel = (unsigned int)bkt; break; }
        run += c;
      }
      shp = pref | (sel << shift);
      shr = k - run;
    }
    __syncthreads();
  }
  const float thr = __uint_as_float(shp);

  // in-bin CE: candidates with 0 < v <= thr (v==0 -> pos element -> no CE)
  double acc = 0.0;
  for (unsigned int i = tid; i < n; i += 256) {
    const float v = __uint_as_float(lst[i]);
    if (v > 0.0f && v <= thr) acc += (double)(-logf(v));
  }
  __shared__ double sd[256];
  sd[tid] = acc;
  __syncthreads();
  for (int o = 128; o > 0; o >>= 1) {
    if (tid < o) sd[tid] += sd[tid + o];
    __syncthreads();
  }
  if (tid == 0) {
    const ScaleScal& ss = scal[s];
    const double Ns = (s == 0) ? (double)N0 : (s == 1) ? (double)N1 : (double)N2;
    const double W = (s == 0) ? 160.0 : (s == 1) ? 80.0 : 40.0;
    const double ls = (ss.sum_pos_ce + ss.ce_below + sd[0]) / (2.0 * Ns);
    const double lb = (ss.sum_diff2 / W) / (4.0 * (double)ss.pos_cnt);
    out[s] = (float)(ls + lb);
  }
}

extern "C" void kernel_launch(void* const* d_in, const int* in_sizes, int n_in,
                              void* d_out, int out_size, void* d_ws,
                              size_t ws_size, hipStream_t stream) {
  const float* sc0 = (const float*)d_in[0];
  const float* bb0 = (const float*)d_in[1];
  const float* gl0 = (const float*)d_in[3];
  const float* sc1 = (const float*)d_in[4];
  const float* bb1 = (const float*)d_in[5];
  const float* gl1 = (const float*)d_in[7];
  const float* sc2 = (const float*)d_in[8];
  const float* bb2 = (const float*)d_in[9];
  const float* gl2 = (const float*)d_in[11];

  char* ws = (char*)d_ws;
  unsigned int* hist = (unsigned int*)ws;              // 3*256 u32
  float* histce = (float*)(hist + 3 * LBINS);          // 3*256 f32
  unsigned int* cand_cnt = (unsigned int*)(histce + 3 * LBINS);  // 3 (+pad)
  size_t zbytes = (size_t)3 * LBINS * 4 * 2 + 64;      // zeroed region
  zbytes = (zbytes + 255) & ~(size_t)255;              // 6400 B
  ScaleScal* scal = (ScaleScal*)(ws + zbytes);         // 3 * 40 B (written)
  size_t off = zbytes + 256;
  P1* part1 = (P1*)(ws + off);                         // NBLK * 32 B
  off += (size_t)NBLK * sizeof(P1);
  off = (off + 255) & ~(size_t)255;
  unsigned int* cand = (unsigned int*)(ws + off);      // 3*CAP u32
  off += (size_t)3 * CAP * 4;
  off = (off + 255) & ~(size_t)255;
  float* npv = (float*)(ws + off);                     // NT floats

  const dim3 blk(256);
  k_zero<<<dim3(1), blk, 0, stream>>>((uint4*)d_ws, (int)(zbytes >> 4));
  k_pass1<<<dim3(NBLK), blk, 0, stream>>>(sc0, bb0, gl0, sc1, bb1, gl1, sc2,
                                          bb2, gl2, hist, histce, npv, part1);
  k_cand<<<dim3(NBLK), blk, 0, stream>>>(part1, hist, histce, npv, scal,
                                         cand_cnt, cand);
  k_select<<<dim3(3), blk, 0, stream>>>(scal, cand_cnt, cand, (float*)d_out);
}

// Round 9
// 63.372 us; speedup vs baseline: 5.3660x; 1.4449x over previous
//
#include <hip/hip_runtime.h>

// ---------------------------------------------------------------------------
// cross_entropy_with_hnm_for_one_class_detection
//
// 3 scales: softmax-CE with hard-negative mining (k-th order statistic of
// neg_prob over N=B*H*W) + masked bbox MSE. Output: 3 floats.
//
// R8 diagnosis: k_pass1 latency-bound (1 quad/thread, 21% occ, ~1TB/s);
// k_select serial bucket walk; 4 launches. R9: 8 elem/thread with all loads
// up-front; k_cand+k_select fused via per-scale last-block-done (device-
// scope atomics + threadfence); parallel bucket scan. 3 launches:
//   k_zero -> k_pass1 -> k_candsel.
// ---------------------------------------------------------------------------

namespace {
constexpr int HW0 = 25600, HW1 = 6400, HW2 = 1600;
constexpr int N0 = 32 * HW0;  // 819200
constexpr int N1 = 32 * HW1;  // 204800
constexpr int N2 = 32 * HW2;  // 51200

constexpr int LBINS = 256;
constexpr int CAP = 8192;  // candidate capacity per scale

// 2048 elements per block (two float4-quads per thread)
constexpr int B0 = N0 / 2048, B1 = N1 / 2048, B2 = N2 / 2048;  // 400,100,25
constexpr int NBLK = B0 + B1 + B2;                             // 525

struct P1 {
  double posce, diff2;
  unsigned int pcnt, ncnt;
  unsigned long long pad;
};  // 32 B

__device__ inline void scale_of(int bid, int& s, int& rel, int& lo, int& hi) {
  if (bid < B0) {
    s = 0; rel = bid; lo = 0; hi = B0;
  } else if (bid < B0 + B1) {
    s = 1; rel = bid - B0; lo = B0; hi = B0 + B1;
  } else {
    s = 2; rel = bid - B0 - B1; lo = B0 + B1; hi = NBLK;
  }
}

__device__ inline unsigned int lin_bin(float v) {
  unsigned int b = (unsigned int)(v * 256.0f);
  return b > 255u ? 255u : b;
}
}  // namespace

// ---------------- pass 0: zero control region (6.4 KB) ----------------------
__global__ __launch_bounds__(256) void k_zero(uint4* __restrict__ p, int n4) {
  for (int i = threadIdx.x; i < n4; i += 256) p[i] = make_uint4(0u, 0u, 0u, 0u);
}

// ---------------- pass 1: softmax, counts, pos-CE, bbox, hist + CE hist -----
template <int HW>
__device__ void pass1_body(int rel, const float* __restrict__ sc,
                           const float* __restrict__ bb,
                           const float* __restrict__ gl,
                           unsigned int* __restrict__ hist,
                           float* __restrict__ histce,
                           float* __restrict__ npv, P1* __restrict__ p1) {
  __shared__ unsigned int lh[4][LBINS];  // wave-private, 4 KiB
  __shared__ float lhe[4][LBINS];        // 4 KiB
  const int tid = threadIdx.x;
  const int wid = tid >> 6;
#pragma unroll
  for (int w = 0; w < 4; ++w) {
    lh[w][tid] = 0u;
    lhe[w][tid] = 0.0f;
  }
  __syncthreads();

  // two quad-groups; issue all 8 global loads before any math (ILP)
  const int q0 = (rel * 512 + tid) * 4;
  const int q1 = q0 + 1024;
  const int bA = q0 / HW, hwA = q0 - bA * HW;
  const int bB = q1 / HW, hwB = q1 - bB * HW;
  const float* scA = sc + (size_t)bA * 2 * HW + hwA;
  const float* scB = sc + (size_t)bB * 2 * HW + hwB;
  const float* glA = gl + (size_t)bA * 6 * HW + hwA;
  const float* glB = gl + (size_t)bB * 6 * HW + hwB;
  const float4 s0A = *(const float4*)scA;
  const float4 s1A = *(const float4*)(scA + HW);
  const float4 l0A = *(const float4*)glA;
  const float4 l1A = *(const float4*)(glA + HW);
  const float4 s0B = *(const float4*)scB;
  const float4 s1B = *(const float4*)(scB + HW);
  const float4 l0B = *(const float4*)glB;
  const float4 l1B = *(const float4*)(glB + HW);

  double posce = 0.0, diff2 = 0.0;
  unsigned int pcnt = 0, ncnt = 0;

  auto process = [&](const float4& s0v, const float4& s1v, const float4& l0v,
                     const float4& l1v, const float* __restrict__ glq,
                     const float* __restrict__ bbq, float* __restrict__ npq) {
    const float s0a[4] = {s0v.x, s0v.y, s0v.z, s0v.w};
    const float s1a[4] = {s1v.x, s1v.y, s1v.z, s1v.w};
    const float l0a[4] = {l0v.x, l0v.y, l0v.z, l0v.w};
    const float l1a[4] = {l1v.x, l1v.y, l1v.z, l1v.w};
    float np[4];
#pragma unroll
    for (int j = 0; j < 4; ++j) {
      const float d = s1a[j] - s0a[j];
      const float t = expf(-fabsf(d));
      const float l1p = log1pf(t);  // lse after max-sub
      const bool pos = l0a[j] > 0.5f;
      const bool neg = l1a[j] > 0.5f;
      const float sm1 = ((d >= 0.0f) ? 1.0f : t) / (1.0f + t);
      const float v = neg ? sm1 : 0.0f;
      np[j] = v;
      const unsigned int bin = lin_bin(v);
      atomicAdd(&lh[wid][bin], 1u);
      if (neg) {
        ncnt++;
        const float ce = l1p - ((d >= 0.0f) ? 0.0f : d);  // -log_softmax[1]
        atomicAdd(&lhe[wid][bin], ce);
      }
      if (pos) {
        pcnt++;
        const float ls0 = ((d > 0.0f) ? -d : 0.0f) - l1p;
        posce += (double)(-l0a[j] * ls0);
        float acc = 0.0f;
#pragma unroll
        for (int c = 0; c < 4; ++c) {
          const float dd = glq[(2 + c) * HW + j] - bbq[c * HW + j];
          acc += dd * dd;
        }
        diff2 += (double)acc;
      }
    }
    *(float4*)npq = make_float4(np[0], np[1], np[2], np[3]);
  };
  process(s0A, s1A, l0A, l1A, glA, bb + (size_t)bA * 4 * HW + hwA, npv + q0);
  process(s0B, s1B, l0B, l1B, glB, bb + (size_t)bB * 4 * HW + hwB, npv + q1);

  __syncthreads();
  {  // flush: one bin per thread per array
    const unsigned int c = lh[0][tid] + lh[1][tid] + lh[2][tid] + lh[3][tid];
    if (c) atomicAdd(&hist[tid], c);  // u32 HW atomic
    const float e = lhe[0][tid] + lhe[1][tid] + lhe[2][tid] + lhe[3][tid];
    if (e != 0.0f) atomicAdd(&histce[tid], e);  // f32 HW atomic
  }

  // wave shuffle-reduce, then 4 partials -> thread 0
  for (int o = 32; o > 0; o >>= 1) {
    posce += __shfl_down(posce, o, 64);
    diff2 += __shfl_down(diff2, o, 64);
    pcnt += __shfl_down(pcnt, o, 64);
    ncnt += __shfl_down(ncnt, o, 64);
  }
  __shared__ double wa[4], wb[4];
  __shared__ unsigned int wc[4], wd[4];
  if ((tid & 63) == 0) {
    wa[wid] = posce; wb[wid] = diff2; wc[wid] = pcnt; wd[wid] = ncnt;
  }
  __syncthreads();
  if (tid == 0) {
    p1->posce = wa[0] + wa[1] + wa[2] + wa[3];
    p1->diff2 = wb[0] + wb[1] + wb[2] + wb[3];
    p1->pcnt = wc[0] + wc[1] + wc[2] + wc[3];
    p1->ncnt = wd[0] + wd[1] + wd[2] + wd[3];
  }
}

__global__ __launch_bounds__(256, 4) void k_pass1(
    const float* sc0, const float* bb0, const float* gl0,
    const float* sc1, const float* bb1, const float* gl1,
    const float* sc2, const float* bb2, const float* gl2,
    unsigned int* hist, float* histce, float* npv, P1* part1) {
  int s, rel, lo, hi;
  scale_of(blockIdx.x, s, rel, lo, hi);
  P1* p1 = part1 + blockIdx.x;
  if (s == 0)
    pass1_body<HW0>(rel, sc0, bb0, gl0, hist, histce, npv, p1);
  else if (s == 1)
    pass1_body<HW1>(rel, sc1, bb1, gl1, hist + LBINS, histce + LBINS, npv + N0,
                    p1);
  else
    pass1_body<HW2>(rel, sc2, bb2, gl2, hist + 2 * LBINS, histce + 2 * LBINS,
                    npv + N0 + N1, p1);
}

// --- pass 2: redundant mid + gather; LAST block per scale selects+finalizes -
__global__ __launch_bounds__(256) void k_candsel(
    const P1* __restrict__ part1, const unsigned int* __restrict__ hist,
    const float* __restrict__ histce, const float* __restrict__ npv,
    unsigned int* __restrict__ cand_cnt, unsigned int* __restrict__ cand,
    unsigned int* __restrict__ done, float* __restrict__ out) {
  const int tid = threadIdx.x;
  int s, rel, lo, hi;
  scale_of(blockIdx.x, s, rel, lo, hi);
  const int base = (s == 0) ? 0 : (s == 1) ? N0 : N0 + N1;
  const int nblk_s = hi - lo;

  // ---- redundant per-block: reduce per-block partials of this scale
  __shared__ double sda[256], sdb[256];
  __shared__ unsigned int sua[256], sub[256];
  {
    double a = 0.0, b2 = 0.0;
    unsigned int c = 0, d = 0;
    for (int i = lo + tid; i < hi; i += 256) {
      const P1 p = part1[i];
      a += p.posce; b2 += p.diff2; c += p.pcnt; d += p.ncnt;
    }
    sda[tid] = a; sdb[tid] = b2; sua[tid] = c; sub[tid] = d;
  }
  __syncthreads();
  for (int o = 128; o > 0; o >>= 1) {
    if (tid < o) {
      sda[tid] += sda[tid + o]; sdb[tid] += sdb[tid + o];
      sua[tid] += sua[tid + o]; sub[tid] += sub[tid + o];
    }
    __syncthreads();
  }
  __shared__ double sh_posce, sh_diff2;
  __shared__ unsigned int sh_pcnt, sh_k;
  if (tid == 0) {
    sh_posce = sda[0];
    sh_diff2 = sdb[0];
    sh_pcnt = sua[0];
    const unsigned long long k10 = 10ull * (unsigned long long)sua[0];
    sh_k = (k10 < (unsigned long long)sub[0]) ? (unsigned int)k10 : sub[0];
  }
  __syncthreads();

  // ---- redundant per-block: dual inclusive scan over 256 bins
  __shared__ unsigned int partC[256];
  __shared__ double partE[256];
  __shared__ unsigned int sh_selb, sh_selr;
  __shared__ double sh_ceb;
  const unsigned int ownC = hist[s * LBINS + tid];
  const double ownE = (double)histce[s * LBINS + tid];
  partC[tid] = ownC;
  partE[tid] = ownE;
  __syncthreads();
  for (int o = 1; o < 256; o <<= 1) {
    const unsigned int aC = (tid >= o) ? partC[tid - o] : 0u;
    const double aE = (tid >= o) ? partE[tid - o] : 0.0;
    __syncthreads();
    partC[tid] += aC;
    partE[tid] += aE;
    __syncthreads();
  }
  {
    const unsigned int k = sh_k;
    const unsigned int inclC = partC[tid];
    const unsigned int exclC = inclC - ownC;
    if (ownC && k >= exclC && k < inclC) {  // unique winner thread
      sh_selb = (unsigned int)tid;
      sh_selr = k - exclC;
      sh_ceb = partE[tid] - ownE;  // exclusive CE prefix
    }
  }
  __syncthreads();

  // ---- gather candidates (block-aggregated reservation, 1 atomic/block)
  __shared__ unsigned int cbuf[2048];
  __shared__ unsigned int ccnt, cbase;
  if (tid == 0) ccnt = 0u;
  __syncthreads();
  {
    const unsigned int bsel = sh_selb;
#pragma unroll
    for (int g = 0; g < 2; ++g) {
      const int q = (rel * 512 + g * 256 + tid) * 4;
      const float4 v4 = *(const float4*)(npv + base + q);
      const float va[4] = {v4.x, v4.y, v4.z, v4.w};
#pragma unroll
      for (int j = 0; j < 4; ++j) {
        if (lin_bin(va[j]) == bsel) {
          const unsigned int sl = atomicAdd(&ccnt, 1u);
          cbuf[sl] = __float_as_uint(va[j]);
        }
      }
    }
  }
  __syncthreads();
  if (tid == 0 && ccnt) cbase = atomicAdd(&cand_cnt[s], ccnt);
  __syncthreads();
  const unsigned int cn = ccnt;
  for (unsigned int i = tid; i < cn; i += 256) {
    const unsigned int idx = cbase + i;
    if (idx < CAP) cand[s * CAP + idx] = cbuf[i];
  }

  // ---- last-block-done: winner runs selection + finalize
  __shared__ unsigned int rank_old;
  __syncthreads();
  if (tid == 0) {
    __threadfence();  // release: candidate stores visible before count
    rank_old = atomicAdd(&done[s], 1u);
  }
  __syncthreads();
  if (rank_old != (unsigned int)(nblk_s - 1)) return;
  __threadfence();  // acquire: see all blocks' candidate stores

  const unsigned int n = min(cand_cnt[s], (unsigned int)CAP);
  const unsigned int* lst = cand + s * CAP;
  __shared__ unsigned int dh[256];
  __shared__ unsigned int shp, shr, sh_w8, sh_nr;
  if (tid == 0) {
    shr = sh_selr;
    // bins >=1 span at most one binade -> candidates share bits 31:24
    shp = (sh_selb >= 1u) ? (lst[0] & 0xFF000000u) : 0u;
  }
  __syncthreads();
  const int r0 = (sh_selb >= 1u) ? 1 : 0;
  for (int round = r0; round < 4; ++round) {
    const int shift = 24 - 8 * round;
    dh[tid] = 0u;
    __syncthreads();
    const unsigned int pref = shp;
    for (unsigned int i = tid; i < n; i += 256) {
      const unsigned int v = lst[i];
      const bool match =
          (round == 0) || ((v >> (shift + 8)) == (pref >> (shift + 8)));
      if (match) atomicAdd(&dh[(v >> shift) & 255u], 1u);
    }
    __syncthreads();
    const unsigned int own = dh[tid];
    for (int o = 1; o < 256; o <<= 1) {  // inclusive scan in place
      const unsigned int add = (tid >= o) ? dh[tid - o] : 0u;
      __syncthreads();
      dh[tid] += add;
      __syncthreads();
    }
    const unsigned int incl = dh[tid];
    const unsigned int excl = incl - own;
    const unsigned int k = shr;
    if (own && k >= excl && k < incl) {
      sh_w8 = (unsigned int)tid;
      sh_nr = k - excl;
    }
    __syncthreads();
    if (tid == 0) {
      shp = pref | (sh_w8 << shift);
      shr = sh_nr;
    }
    __syncthreads();
  }
  const float thr = __uint_as_float(shp);

  // in-bin CE: candidates with 0 < v <= thr (v==0 -> non-neg -> no CE)
  double acc = 0.0;
  for (unsigned int i = tid; i < n; i += 256) {
    const float v = __uint_as_float(lst[i]);
    if (v > 0.0f && v <= thr) acc += (double)(-logf(v));
  }
  sda[tid] = acc;
  __syncthreads();
  for (int o = 128; o > 0; o >>= 1) {
    if (tid < o) sda[tid] += sda[tid + o];
    __syncthreads();
  }
  if (tid == 0) {
    const double Ns = (s == 0) ? (double)N0 : (s == 1) ? (double)N1 : (double)N2;
    const double W = (s == 0) ? 160.0 : (s == 1) ? 80.0 : 40.0;
    const double ls = (sh_posce + sh_ceb + sda[0]) / (2.0 * Ns);
    const double lb = (sh_diff2 / W) / (4.0 * (double)sh_pcnt);
    out[s] = (float)(ls + lb);
  }
}

extern "C" void kernel_launch(void* const* d_in, const int* in_sizes, int n_in,
                              void* d_out, int out_size, void* d_ws,
                              size_t ws_size, hipStream_t stream) {
  const float* sc0 = (const float*)d_in[0];
  const float* bb0 = (const float*)d_in[1];
  const float* gl0 = (const float*)d_in[3];
  const float* sc1 = (const float*)d_in[4];
  const float* bb1 = (const float*)d_in[5];
  const float* gl1 = (const float*)d_in[7];
  const float* sc2 = (const float*)d_in[8];
  const float* bb2 = (const float*)d_in[9];
  const float* gl2 = (const float*)d_in[11];

  char* ws = (char*)d_ws;
  unsigned int* hist = (unsigned int*)ws;              // 3*256 u32
  float* histce = (float*)(hist + 3 * LBINS);          // 3*256 f32
  unsigned int* cand_cnt = (unsigned int*)(histce + 3 * LBINS);  // 3 u32
  unsigned int* done = cand_cnt + 8;                   // 3 u32
  size_t zbytes = (size_t)3 * LBINS * 4 * 2 + 64;      // zeroed region
  zbytes = (zbytes + 255) & ~(size_t)255;              // 6400 B
  size_t off = zbytes;
  P1* part1 = (P1*)(ws + off);                         // NBLK * 32 B
  off += (size_t)NBLK * sizeof(P1);
  off = (off + 255) & ~(size_t)255;
  unsigned int* cand = (unsigned int*)(ws + off);      // 3*CAP u32
  off += (size_t)3 * CAP * 4;
  off = (off + 255) & ~(size_t)255;
  float* npv = (float*)(ws + off);                     // NT floats

  const dim3 blk(256);
  k_zero<<<dim3(1), blk, 0, stream>>>((uint4*)d_ws, (int)(zbytes >> 4));
  k_pass1<<<dim3(NBLK), blk, 0, stream>>>(sc0, bb0, gl0, sc1, bb1, gl1, sc2,
                                          bb2, gl2, hist, histce, npv, part1);
  k_candsel<<<dim3(NBLK), blk, 0, stream>>>(part1, hist, histce, npv, cand_cnt,
                                            cand, done, (float*)d_out);
}